// Round 10
// baseline (514.486 us; speedup 1.0000x reference)
//
#include <hip/hip_runtime.h>
#include <hip/hip_bf16.h>
#include <math.h>

#define BSHIFT 9                 // 512 nodes per bucket
#define NBUCK(N) (((N) + 511) >> 9)
#define TILE 8192                // edges per partition block
#define CAP 20480                // max edges per bucket (mean 16896, ~28-sigma headroom)

typedef short bf16x8 __attribute__((ext_vector_type(8)));
typedef float f32x16 __attribute__((ext_vector_type(16)));

// ---- bf16 helpers ---------------------------------------------------------
__device__ __forceinline__ unsigned short f2bf(float f) {
    unsigned u = __float_as_uint(f);
    u += 0x7fffu + ((u >> 16) & 1u);      // RNE
    return (unsigned short)(u >> 16);
}
__device__ __forceinline__ unsigned packbf2(float lo, float hi) {
    return (unsigned)f2bf(lo) | ((unsigned)f2bf(hi) << 16);
}
__device__ __forceinline__ float bf_lo(unsigned u) { return __uint_as_float(u << 16); }
__device__ __forceinline__ float bf_hi(unsigned u) { return __uint_as_float(u & 0xffff0000u); }

// ---- partition: edges -> fixed-stride dst-buckets & src-buckets -----------
// LDS-staged; flush is chunk-parallel: every lane stores every pass, bucket
// found by 8-step binary search in the block-local offset table.
__global__ __launch_bounds__(256) void part_kernel(
    const int* __restrict__ src, const int* __restrict__ dst,
    int* __restrict__ gcurD, int* __restrict__ gcurS,
    int* __restrict__ gbufD, unsigned short* __restrict__ gbufS, int E, int K) {
    __shared__ int cD[256], bD[256], cS[256], bS[256];
    __shared__ int oD[257], oS[257];
    __shared__ int sbufD[TILE];              // 32 KB staging (packed entries)
    __shared__ unsigned short sbufS[TILE];   // 16 KB staging (local src)
    const int t = threadIdx.x;
    const int tile = blockIdx.x * TILE;

    cD[t] = 0; cS[t] = 0;
    __syncthreads();

    int dv[32];
    #pragma unroll
    for (int i = 0; i < 32; ++i) {
        const int e = tile + i * 256 + t;
        dv[i] = (e < E) ? dst[e] : -1;
        if (dv[i] >= 0) {
            atomicAdd(&cD[dv[i] >> BSHIFT], 1);
            atomicAdd(&cS[src[e] >> BSHIFT], 1);
        }
    }
    __syncthreads();

    // direct exclusive scans over 256 bucket counters
    {
        const int v = cD[t];
        oD[t] = v;
        __syncthreads();
        for (int off = 1; off < 256; off <<= 1) {
            int x = (t >= off) ? oD[t - off] : 0;
            __syncthreads(); oD[t] += x; __syncthreads();
        }
        const int incl = oD[t];
        __syncthreads();
        oD[t] = incl - v;
        if (t == K - 1) oD[K] = incl;
    }
    {
        const int v = cS[t];
        oS[t] = v;
        __syncthreads();
        for (int off = 1; off < 256; off <<= 1) {
            int x = (t >= off) ? oS[t - off] : 0;
            __syncthreads(); oS[t] += x; __syncthreads();
        }
        const int incl = oS[t];
        __syncthreads();
        oS[t] = incl - v;
        if (t == K - 1) oS[K] = incl;
    }
    __syncthreads();

    // reserve global runs (one atomic per non-empty bucket); reset cursors
    if (t < K) {
        int c = cD[t];
        bD[t] = (c ? atomicAdd(&gcurD[t], c) : 0) + t * CAP;
        c = cS[t];
        bS[t] = (c ? atomicAdd(&gcurS[t], c) : 0) + t * CAP;
    }
    cD[t] = 0; cS[t] = 0;
    __syncthreads();

    // scatter into LDS staging (bucket-contiguous)
    #pragma unroll
    for (int i = 0; i < 32; ++i) {
        if (dv[i] >= 0) {
            const int e = tile + i * 256 + t;
            const int sv = src[e];
            const int b1 = dv[i] >> BSHIFT;
            const int p1 = oD[b1] + atomicAdd(&cD[b1], 1);
            sbufD[p1] = ((dv[i] & 511) << 17) | sv;
            const int b2 = sv >> BSHIFT;
            const int p2 = oS[b2] + atomicAdd(&cS[b2], 1);
            sbufS[p2] = (unsigned short)(sv & 511);
        }
    }
    __syncthreads();

    // flush: waves take contiguous 64-entry chunks; lane binary-searches its
    // bucket; writes are piecewise-consecutive runs issued the same instant.
    const int wv = t >> 6, lane = t & 63;
    const int totD = oD[K];
    for (int b0 = wv << 6; b0 < totD; b0 += 256) {
        const int idx = b0 + lane;
        if (idx < totD) {
            int lo = 0, hi = K;
            while (hi - lo > 1) { const int mid = (lo + hi) >> 1; if (idx >= oD[mid]) lo = mid; else hi = mid; }
            gbufD[bD[lo] + (idx - oD[lo])] = sbufD[idx];
        }
    }
    const int totS = oS[K];
    for (int b0 = wv << 6; b0 < totS; b0 += 256) {
        const int idx = b0 + lane;
        if (idx < totS) {
            int lo = 0, hi = K;
            while (hi - lo > 1) { const int mid = (lo + hi) >> 1; if (idx >= oS[mid]) lo = mid; else hi = mid; }
            gbufS[bS[lo] + (idx - oS[lo])] = sbufS[idx];
        }
    }
}

// ---- fillD: per dst-bucket (512 nodes): indeg, rowstart, ndst, CSR --------
__global__ __launch_bounds__(256) void fillD_kernel(
    const int* __restrict__ cntD, const int* __restrict__ gbufD,
    int* __restrict__ csr_src, int* __restrict__ rowstart, int* __restrict__ indeg,
    float* __restrict__ ndst, int N, int K) {
    __shared__ int cnt[512];
    __shared__ int ps[256];
    __shared__ int cur[512];
    const int t = threadIdx.x;
    const int b = blockIdx.x;
    const int n0 = b << BSHIFT;
    const int bs = b * CAP;
    const int be = bs + cntD[b];
    cnt[t] = 0; cnt[t + 256] = 0;
    __syncthreads();
    for (int idx = bs + t; idx < be; idx += 256)
        atomicAdd(&cnt[gbufD[idx] >> 17], 1);
    __syncthreads();
    const int d0 = cnt[2 * t], d1 = cnt[2 * t + 1];
    ps[t] = d0 + d1;
    __syncthreads();
    for (int off = 1; off < 256; off <<= 1) {
        int x = (t >= off) ? ps[t - off] : 0;
        __syncthreads(); ps[t] += x; __syncthreads();
    }
    const int base = ps[t] - d0 - d1;
    const int rs0 = bs + base;
    const int rs1 = rs0 + d0;
    cur[2 * t] = rs0; cur[2 * t + 1] = rs1;
    const int n = n0 + 2 * t;
    if (n < N) {
        rowstart[n] = rs0; indeg[n] = d0;
        ndst[n] = rsqrtf((float)d0);        // self-loops => deg >= 1
    }
    if (n + 1 < N) {
        rowstart[n + 1] = rs1; indeg[n + 1] = d1;
        ndst[n + 1] = rsqrtf((float)d1);
    }
    __syncthreads();
    for (int idx = bs + t; idx < be; idx += 256) {
        const int p = gbufD[idx];
        const int pos = atomicAdd(&cur[p >> 17], 1);
        csr_src[pos] = p & 131071;
    }
}

// ---- fillS: per src-bucket (512 nodes): outdeg -> nsrc --------------------
__global__ __launch_bounds__(256) void fillS_kernel(
    const int* __restrict__ cntS, const unsigned short* __restrict__ gbufS,
    float* __restrict__ nsrc, int N, int K) {
    __shared__ int cnt[512];
    const int t = threadIdx.x;
    const int b = blockIdx.x;
    const int bs = b * CAP;
    const int be = bs + cntS[b];
    cnt[t] = 0; cnt[t + 256] = 0;
    __syncthreads();
    for (int idx = bs + t; idx < be; idx += 256)
        atomicAdd(&cnt[gbufS[idx]], 1);
    __syncthreads();
    const int n = (b << BSHIFT) + 2 * t;
    if (n < N) nsrc[n] = rsqrtf((float)cnt[2 * t]);
    if (n + 1 < N) nsrc[n + 1] = rsqrtf((float)cnt[2 * t + 1]);
}

// ---- GEMM1 (MFMA): h1[n][j] = bf16( nsrc[n] * sum_k feat[n][k]*W1[k][j] ) -
__global__ __launch_bounds__(256) void gemm1_kernel(
    const float* __restrict__ feat, const float* __restrict__ W1,
    const float* __restrict__ nsrc, unsigned short* __restrict__ h1, int N) {
    __shared__ short W1t[32 * 264];    // 16.9 KB: W1t[c][k] = bf16(W1[k][c])
    const int t = threadIdx.x;
    for (int i = t; i < 8192; i += 256) {
        const int k = i >> 5, c = i & 31;
        W1t[c * 264 + k] = (short)f2bf(W1[i]);
    }
    __syncthreads();

    const int l  = t & 63;
    const int wv = t >> 6;
    const int base = blockIdx.x * 128 + wv * 32;
    const int m  = l & 31;
    const int kh = (l >> 5) << 3;
    int r = base + m;
    if (r >= N) r = N - 1;
    const float* fr = feat + (size_t)r * 256 + kh;
    const short* wr = &W1t[m * 264 + kh];

    f32x16 acc;
    #pragma unroll
    for (int i = 0; i < 16; ++i) acc[i] = 0.f;

    #pragma unroll
    for (int kb = 0; kb < 16; ++kb) {
        const float4 f0 = *(const float4*)(fr + kb * 16);
        const float4 f1 = *(const float4*)(fr + kb * 16 + 4);
        bf16x8 a;
        a[0] = (short)f2bf(f0.x); a[1] = (short)f2bf(f0.y);
        a[2] = (short)f2bf(f0.z); a[3] = (short)f2bf(f0.w);
        a[4] = (short)f2bf(f1.x); a[5] = (short)f2bf(f1.y);
        a[6] = (short)f2bf(f1.z); a[7] = (short)f2bf(f1.w);
        const bf16x8 b = *(const bf16x8*)(wr + kb * 16);
        acc = __builtin_amdgcn_mfma_f32_32x32x16_bf16(a, b, acc, 0, 0, 0);
    }

    const int rbase = base + ((l >> 5) << 2);
    #pragma unroll
    for (int reg = 0; reg < 16; ++reg) {
        const int row = rbase + (reg & 3) + ((reg >> 2) << 3);
        if (row < N)
            h1[(size_t)row * 32 + m] = f2bf(acc[reg] * nsrc[row]);
    }
}

// ---- agg1: x1s[n] = bf16( relu(ndst[n]*sum h1[src] + b1) * nsrc[n] ) ------
__global__ __launch_bounds__(256) void agg1_kernel(
    const int* __restrict__ csr_src, const int* __restrict__ rowstart,
    const int* __restrict__ indeg, const unsigned* __restrict__ h1,
    const float* __restrict__ ndst, const float* __restrict__ nsrc,
    const float* __restrict__ b1, unsigned* __restrict__ x1s, int N) {
    const int t = threadIdx.x;
    const int n = blockIdx.x * 64 + (t >> 2);
    if (n >= N) return;
    const int c = t & 3;
    const int rs = rowstart[n];
    const int re = rs + indeg[n];
    float a0=0.f,a1=0.f,a2=0.f,a3=0.f,a4=0.f,a5=0.f,a6=0.f,a7=0.f;
    const uint4* H = (const uint4*)h1;
    for (int k = rs; k < re; ++k) {
        const int s = csr_src[k];
        const uint4 q = H[(size_t)s * 4 + c];
        a0 += bf_lo(q.x); a1 += bf_hi(q.x);
        a2 += bf_lo(q.y); a3 += bf_hi(q.y);
        a4 += bf_lo(q.z); a5 += bf_hi(q.z);
        a6 += bf_lo(q.w); a7 += bf_hi(q.w);
    }
    const float nd = ndst[n];
    const float ns = nsrc[n];
    const float* bb = b1 + c * 8;
    float x0 = fmaxf(a0 * nd + bb[0], 0.f) * ns;
    float x1 = fmaxf(a1 * nd + bb[1], 0.f) * ns;
    float x2 = fmaxf(a2 * nd + bb[2], 0.f) * ns;
    float x3 = fmaxf(a3 * nd + bb[3], 0.f) * ns;
    float x4 = fmaxf(a4 * nd + bb[4], 0.f) * ns;
    float x5 = fmaxf(a5 * nd + bb[5], 0.f) * ns;
    float x6 = fmaxf(a6 * nd + bb[6], 0.f) * ns;
    float x7 = fmaxf(a7 * nd + bb[7], 0.f) * ns;
    uint4 o;
    o.x = packbf2(x0, x1); o.y = packbf2(x2, x3);
    o.z = packbf2(x4, x5); o.w = packbf2(x6, x7);
    ((uint4*)x1s)[(size_t)n * 4 + c] = o;
}

// ---- agg2: a2[n] = ndst[n] * sum x1s[src]   (fp32 out, 32-wide) -----------
__global__ __launch_bounds__(256) void agg2_kernel(
    const int* __restrict__ csr_src, const int* __restrict__ rowstart,
    const int* __restrict__ indeg, const unsigned* __restrict__ x1s,
    const float* __restrict__ ndst, float* __restrict__ a2out, int N) {
    const int t = threadIdx.x;
    const int n = blockIdx.x * 64 + (t >> 2);
    if (n >= N) return;
    const int c = t & 3;
    const int rs = rowstart[n];
    const int re = rs + indeg[n];
    float a0=0.f,a1=0.f,a2=0.f,a3=0.f,a4=0.f,a5=0.f,a6=0.f,a7=0.f;
    const uint4* H = (const uint4*)x1s;
    for (int k = rs; k < re; ++k) {
        const int s = csr_src[k];
        const uint4 q = H[(size_t)s * 4 + c];
        a0 += bf_lo(q.x); a1 += bf_hi(q.x);
        a2 += bf_lo(q.y); a3 += bf_hi(q.y);
        a4 += bf_lo(q.z); a5 += bf_hi(q.z);
        a6 += bf_lo(q.w); a7 += bf_hi(q.w);
    }
    const float nd = ndst[n];
    float4 o0 = {a0 * nd, a1 * nd, a2 * nd, a3 * nd};
    float4 o1 = {a4 * nd, a5 * nd, a6 * nd, a7 * nd};
    *(float4*)&a2out[(size_t)n * 32 + c * 8] = o0;
    *(float4*)&a2out[(size_t)n * 32 + c * 8 + 4] = o1;
}

// ---- final: out = log_softmax(a2 @ W2 + b2), one wave per node ------------
__global__ __launch_bounds__(256) void final_kernel(
    const float* __restrict__ a2, const float* __restrict__ W2,
    const float* __restrict__ b2, float* __restrict__ out, int N) {
    __shared__ float sW2[32 * 40];
    __shared__ float sb2[40];
    const int t = threadIdx.x;
    for (int i = t; i < 1280; i += 256) sW2[i] = W2[i];
    if (t < 40) sb2[t] = b2[t];
    __syncthreads();
    const int lane = t & 63;
    const int n = blockIdx.x * 4 + (t >> 6);
    if (n >= N) return;
    const float v = a2[(size_t)n * 32 + (lane & 31)];
    const int jj = (lane < 40) ? lane : 39;
    float z = sb2[jj];
    #pragma unroll
    for (int k = 0; k < 32; ++k) {
        const float ak = __shfl(v, k, 64);
        z += ak * sW2[k * 40 + jj];
    }
    if (lane >= 40) z = -INFINITY;
    float m = z;
    #pragma unroll
    for (int off = 32; off; off >>= 1) m = fmaxf(m, __shfl_xor(m, off, 64));
    float e = (lane < 40) ? __expf(z - m) : 0.f;
    float s = e;
    #pragma unroll
    for (int off = 32; off; off >>= 1) s += __shfl_xor(s, off, 64);
    if (lane < 40) out[(size_t)n * 40 + lane] = z - m - __logf(s);
}

extern "C" void kernel_launch(void* const* d_in, const int* in_sizes, int n_in,
                              void* d_out, int out_size, void* d_ws, size_t ws_size,
                              hipStream_t stream) {
    const float* feat = (const float*)d_in[0];
    const int*   src  = (const int*)d_in[1];
    const int*   dst  = (const int*)d_in[2];
    const float* W1   = (const float*)d_in[3];
    const float* b1   = (const float*)d_in[4];
    const float* W2   = (const float*)d_in[5];
    const float* b2   = (const float*)d_in[6];
    float* out = (float*)d_out;

    const int N = in_sizes[0] / 256;   // 100000
    const int E = in_sizes[1];         // 3300000
    const int K = NBUCK(N);            // 196 buckets of 512 nodes

    // layout: nsrc/ndst fp32, h1/x1s bf16 (64 B rows), a2 fp32, CSR ints.
    char* p = (char*)d_ws;
    float* nsrc = (float*)p;                 p += (size_t)N * 4;        // 400 KB
    float* ndst = (float*)p;                 p += (size_t)N * 4;
    unsigned* h1  = (unsigned*)p;            p += (size_t)N * 64;       // 6.4 MB
    unsigned* x1s = (unsigned*)p;            p += (size_t)N * 64;       // 6.4 MB
    float* a2 = (float*)p;                   p += (size_t)N * 128;      // 12.8 MB
    int* rowstart = (int*)p;                 p += (size_t)N * 4;
    int* indeg_i  = (int*)p;                 p += (size_t)N * 4;
    int* gcurD    = (int*)p;                 p += 256 * 4;
    int* gcurS    = (int*)p;                 p += 256 * 4;
    int* csr_src  = (int*)p;                 p += (size_t)K * CAP * 4;  // 16.05 MB
    // transient overlays over [h1, x1s, a2] (25.6 MB dead during CSR build):
    int* gbufD = (int*)h1;                                  // K*CAP ints   = 16.05 MB
    unsigned short* gbufS = (unsigned short*)((char*)h1 + (size_t)K * CAP * 4);  // 8.03 MB

    hipMemsetAsync(gcurD, 0, sizeof(int) * 512, stream);   // gcurD + gcurS

    const int PB = (E + TILE - 1) / TILE;

    part_kernel<<<PB, 256, 0, stream>>>(src, dst, gcurD, gcurS, gbufD, gbufS, E, K);
    fillD_kernel<<<K, 256, 0, stream>>>(gcurD, gbufD, csr_src, rowstart, indeg_i, ndst, N, K);
    fillS_kernel<<<K, 256, 0, stream>>>(gcurS, gbufS, nsrc, N, K);

    gemm1_kernel<<<(N + 127) / 128, 256, 0, stream>>>(feat, W1, nsrc, (unsigned short*)h1, N);
    agg1_kernel<<<(N + 63) / 64, 256, 0, stream>>>(csr_src, rowstart, indeg_i, h1, ndst, nsrc, b1, x1s, N);
    agg2_kernel<<<(N + 63) / 64, 256, 0, stream>>>(csr_src, rowstart, indeg_i, x1s, ndst, a2, N);
    final_kernel<<<(N + 3) / 4, 256, 0, stream>>>(a2, W2, b2, out, N);
}